// Round 9
// baseline (341.324 us; speedup 1.0000x reference)
//
#include <hip/hip_runtime.h>

#define A_ALLELES 4096
#define CCH 12     // input channels
#define LW 32      // read window length
#define DH 32      // hidden dim
#define RDF (CCH * LW)          // floats per read = 384
#define CHK 8                   // reads per chunk (wave)
#define MAXCH 14336             // max chunks per source: R/8 + A
#define NBH 3584                // blocks per source = MAXCH/4

typedef __attribute__((ext_vector_type(8)))  short bf16x8;   // 4 VGPRs
typedef __attribute__((ext_vector_type(16))) float f32x16;   // 16 VGPRs

// pack two fp32 -> two bf16 (round-half-up; differs from RNE only on ties)
__device__ inline unsigned pk2(float fa, float fb) {
    const unsigned a = __float_as_uint(fa), b = __float_as_uint(fb);
    return ((a + 0x8000u) >> 16) | ((b + 0x8000u) & 0xffff0000u);
}

// ---------------------------------------------------------------------------
// Kernel 1: per-source exclusive scans (reads + chunks) and chunk table.
// Record: x = (allele<<8) | (first?0x80:0) | len,  y = startRead.
// ---------------------------------------------------------------------------
__global__ __launch_bounds__(256) void scan_kernel(
    const int* __restrict__ c0, const int* __restrict__ c1,
    int2* __restrict__ tbl0, int2* __restrict__ tbl1,
    int* __restrict__ nch)
{
    const int sidx = blockIdx.x;
    const int* __restrict__ c = sidx == 0 ? c0 : c1;
    int2* __restrict__ tbl = sidx == 0 ? tbl0 : tbl1;

    __shared__ int partR[256], partC[256];
    const int tid  = threadIdx.x;
    const int base = tid * 16;

    int loc[16];
    int s = 0, sc = 0;
#pragma unroll
    for (int i = 0; i < 16; ++i) {
        loc[i] = c[base + i];
        s += loc[i];
        sc += (loc[i] + CHK - 1) / CHK;
    }
    partR[tid] = s; partC[tid] = sc;
    __syncthreads();

    for (int st = 1; st < 256; st <<= 1) {
        int vr = (tid >= st) ? partR[tid - st] : 0;
        int vc = (tid >= st) ? partC[tid - st] : 0;
        __syncthreads();
        partR[tid] += vr; partC[tid] += vc;
        __syncthreads();
    }

    int exR = tid ? partR[tid - 1] : 0;
    int exC = tid ? partC[tid - 1] : 0;
#pragma unroll
    for (int i = 0; i < 16; ++i) {
        const int n = loc[i];
        int first = 0x80;
        for (int j = 0; j < n; j += CHK) {
            int len = n - j; if (len > CHK) len = CHK;
            int2 rec;
            rec.x = ((base + i) << 8) | first | len;
            rec.y = exR + j;
            tbl[exC++] = rec;
            first = 0;
        }
        exR += n;
    }
    if (tid == 255) nch[sidx] = partC[255];
}

// ---------------------------------------------------------------------------
// Kernel 2: one wave per 8-read chunk. Load phase = two bursts of 32
// independent global_load_dword (4 reads each, no consume in between ->
// ~8KB/wave in flight). Then per read: 4x pk2 -> one 32x32x16 bf16 MFMA
// (A = W hoisted, bias via C operand, D[row=(reg&3)+8*(reg>>2)+4*h][col=l],
// all HW-verified in rounds 6/8) -> relu-acc. Epilogue: shfl over l, fold
// 1/(32*depth) + W2 head; first-chunk-of-allele (src0) adds b2; 2 atomics.
// No per-wave LDS, no serial read-chain: concurrency 2.5x round 8.
// ---------------------------------------------------------------------------
__global__ __launch_bounds__(256, 4) void main_kernel(
    const float* __restrict__ t0, const float* __restrict__ t1,
    const float* __restrict__ W0, const float* __restrict__ b0,
    const float* __restrict__ W1, const float* __restrict__ b1,
    const float* __restrict__ W2, const float* __restrict__ b2,
    const float* __restrict__ dm0, const float* __restrict__ dm1,
    const int2* __restrict__ tbl0, const int2* __restrict__ tbl1,
    const int* __restrict__ nch,
    float* __restrict__ out)
{
    __shared__ float sW2[2 * 2 * DH];
    __shared__ float sB2[2];

    const int tid = threadIdx.x;
    if (tid < 2 * 2 * DH) sW2[tid] = W2[tid];
    if (tid < 2) sB2[tid] = b2[tid];
    __syncthreads();

    const int w    = tid >> 6;
    const int lane = tid & 63;
    const int src  = (blockIdx.x >= NBH) ? 1 : 0;        // block-uniform
    const int ci   = (blockIdx.x - src * NBH) * 4 + w;

    if (ci >= nch[src]) return;          // after the one barrier: safe

    const int2 rec = (src ? tbl1 : tbl0)[ci];
    const int a         = rec.x >> 8;
    const int len       = rec.x & 0x7f;
    const int firstChnk = rec.x & 0x80;
    const int startRead = rec.y;

    const float* __restrict__ tens = src ? t1 : t0;
    const float* __restrict__ dm   = src ? dm1 : dm0;
    const float* __restrict__ gW   = src ? W1 : W0;
    const float* __restrict__ gB   = src ? b1 : b0;

    const int l = lane & 31;             // B column / D column
    const int h = lane >> 5;             // k-half selector

    // ---- hoisted: A fragment from W: A[m=d=l][k=h*8+j], zero k>=12 -------
    union { bf16x8 v; unsigned u[4]; } Af;
#pragma unroll
    for (int p = 0; p < 4; ++p) {
        const int c0 = h * 8 + 2 * p, c1 = c0 + 1;
        const float f0 = (c0 < CCH) ? gW[l * CCH + c0] : 0.f;
        const float f1 = (c1 < CCH) ? gW[l * CCH + c1] : 0.f;
        Af.u[p] = pk2(f0, f1);
    }
    // ---- hoisted: bias via C operand: C[row=d][col] = b[d] ---------------
    f32x16 cb;
#pragma unroll
    for (int reg = 0; reg < 16; ++reg)
        cb[reg] = gB[(reg & 3) + 8 * (reg >> 2) + 4 * h];

    const float* rb = tens + (size_t)startRead * RDF;
    const int offLo = h * 8 * LW + l;            // c = h*8 + j     (+ j*32)
    const int offHi = (h ? 8 : 4) * LW + l;      // c = 4..7 / dup  (+ j*32)

    float acc[16];
#pragma unroll
    for (int reg = 0; reg < 16; ++reg) acc[reg] = 0.f;

#define PACK_MFMA_ACC(vv) do {                                        \
        union { bf16x8 v; unsigned u[4]; } Bf;                        \
        Bf.u[0] = pk2(vv[0], vv[1]); Bf.u[1] = pk2(vv[2], vv[3]);     \
        Bf.u[2] = pk2(vv[4], vv[5]); Bf.u[3] = pk2(vv[6], vv[7]);     \
        const f32x16 D = __builtin_amdgcn_mfma_f32_32x32x16_bf16(     \
            Af.v, Bf.v, cb, 0, 0, 0);                                 \
        _Pragma("unroll")                                             \
        for (int reg = 0; reg < 16; ++reg)                            \
            acc[reg] += fmaxf(D[reg], 0.f); } while (0)

    if (len == CHK) {                    // fast path (always hit here)
        float va[4][8], vb[4][8];
#pragma unroll
        for (int rr = 0; rr < 4; ++rr) { // burst 1: reads 0..3 (32 loads)
            const float* p = rb + rr * RDF;
#pragma unroll
            for (int j = 0; j < 4; ++j) {
                va[rr][j]     = p[offLo + j * 32];
                va[rr][4 + j] = p[offHi + j * 32];
            }
        }
#pragma unroll
        for (int rr = 0; rr < 4; ++rr) { // burst 2: reads 4..7 (32 loads)
            const float* p = rb + (4 + rr) * RDF;
#pragma unroll
            for (int j = 0; j < 4; ++j) {
                vb[rr][j]     = p[offLo + j * 32];
                vb[rr][4 + j] = p[offHi + j * 32];
            }
        }
#pragma unroll
        for (int rr = 0; rr < 4; ++rr) PACK_MFMA_ACC(va[rr]);
#pragma unroll
        for (int rr = 0; rr < 4; ++rr) PACK_MFMA_ACC(vb[rr]);
    } else {                             // generic tail path
        for (int rr = 0; rr < len; ++rr) {
            const float* p = rb + (size_t)rr * RDF;
            float vv[8];
#pragma unroll
            for (int j = 0; j < 4; ++j) {
                vv[j]     = p[offLo + j * 32];
                vv[4 + j] = p[offHi + j * 32];
            }
            PACK_MFMA_ACC(vv);
        }
    }
#undef PACK_MFMA_ACC

    // reduce over l (cols): masks 1..16 stay within each 32-lane half
#pragma unroll
    for (int reg = 0; reg < 16; ++reg) {
#pragma unroll
        for (int mm = 1; mm < 32; mm <<= 1)
            acc[reg] += __shfl_xor(acc[reg], mm, 64);
    }

    const float scale = 1.f / (32.f * dm[a]);
    float c0s = 0.f, c1s = 0.f;
#pragma unroll
    for (int reg = 0; reg < 16; ++reg) {
        const int d = (reg & 3) + 8 * (reg >> 2) + 4 * h;
        const float pv = acc[reg] * scale;     // partial pooled[a, src*32+d]
        c0s = fmaf(pv, sW2[0 * 2 * DH + src * DH + d], c0s);
        c1s = fmaf(pv, sW2[1 * 2 * DH + src * DH + d], c1s);
    }
    // combine the two h-halves (each held 16 of the 32 d's)
    c0s += __shfl_xor(c0s, 32, 64);
    c1s += __shfl_xor(c1s, 32, 64);

    if (lane == 0) {
        if (src == 0 && firstChnk) { c0s += sB2[0]; c1s += sB2[1]; }
        atomicAdd(&out[a * 2 + 0], c0s);
        atomicAdd(&out[a * 2 + 1], c1s);
    }
}

extern "C" void kernel_launch(void* const* d_in, const int* in_sizes, int n_in,
                              void* d_out, int out_size, void* d_ws, size_t ws_size,
                              hipStream_t stream) {
    const float* t0  = (const float*)d_in[0];
    const float* t1  = (const float*)d_in[1];
    const float* W0  = (const float*)d_in[2];
    const float* b0  = (const float*)d_in[3];
    const float* W1  = (const float*)d_in[4];
    const float* b1  = (const float*)d_in[5];
    const float* W2  = (const float*)d_in[6];
    const float* b2  = (const float*)d_in[7];
    const int*  cnt0 = (const int*)d_in[8];
    const int*  cnt1 = (const int*)d_in[9];
    // d_in[10] = numAllelesPerSite (unused by the reference math)
    const float* dm0 = (const float*)d_in[11];
    const float* dm1 = (const float*)d_in[12];

    // workspace layout: nch[2] | pad | tbl0[MAXCH] int2 | tbl1[MAXCH] int2
    int*  nch  = (int*)d_ws;
    int2* tbl0 = (int2*)((char*)d_ws + 16);
    int2* tbl1 = tbl0 + MAXCH;

    hipMemsetAsync(d_out, 0, (size_t)out_size * sizeof(float), stream);
    scan_kernel<<<2, 256, 0, stream>>>(cnt0, cnt1, tbl0, tbl1, nch);

    main_kernel<<<2 * NBH, 256, 0, stream>>>(
        t0, t1, W0, b0, W1, b1, W2, b2,
        dm0, dm1, tbl0, tbl1, nch, (float*)d_out);
}